// Round 3
// baseline (728.765 us; speedup 1.0000x reference)
//
#include <hip/hip_runtime.h>
#include <hip/hip_cooperative_groups.h>
#include <math.h>

namespace cg = cooperative_groups;

#define BATCH 1024
#define FIN   256
#define HDIM  512
#define PDIM  128
#define GRID  512
#define NTHR  256

typedef unsigned short u16;
typedef __attribute__((ext_vector_type(8))) short short8;
typedef __attribute__((ext_vector_type(4))) float fx4;

#define LOG2E 1.4426950408889634f

__device__ __forceinline__ float b2f(u16 b) {
    return __uint_as_float(((unsigned)b) << 16);
}
__device__ __forceinline__ u16 f2b(float f) {
    unsigned u = __float_as_uint(f);
    u += 0x7fffu + ((u >> 16) & 1u);   // RNE
    return (u16)(u >> 16);
}

#if defined(__has_builtin)
#if __has_builtin(__builtin_amdgcn_exp2f)
#define EXP2(x) __builtin_amdgcn_exp2f(x)
#endif
#endif
#ifndef EXP2
#define EXP2(x) __expf(0.69314718055994531f * (x))
#endif

__device__ __forceinline__ float2 pk_fma(float2 a, float2 b, float2 c) {
    float2 d;
    asm("v_pk_fma_f32 %0, %1, %2, %3" : "=v"(d) : "v"(a), "v"(b), "v"(c));
    return d;
}
__device__ __forceinline__ float2 pk_add(float2 a, float2 b) {
    float2 d;
    asm("v_pk_add_f32 %0, %1, %2" : "=v"(d) : "v"(a), "v"(b));
    return d;
}

// ---- GEMM tile config (64x64x64, 4 waves 2x2, 16x16x32 bf16 MFMA) ----
#define BM 64
#define BN 64
#define BK 64
#define LDK 72                  // +8 pad: b128 fragment reads <=2-way (free)
#define SMEM_U16 (2 * BM * LDK) // 18432 B

struct Args {
    const float *x, *lin0_w, *lin0_b;
    const float *b1_qw, *b1_qb, *b1_kw, *b1_kb, *b1_vw, *b1_vb, *b1_f1w, *b1_f1b;
    const float *b2_qw, *b2_qb, *b2_kw, *b2_kb, *b2_vw, *b2_vb, *b2_f1w, *b2_f1b;
    const float *fea_w, *fea_b, *reg_w, *reg_b;
    float *out, *fea;
    u16 *xb, *wl0, *w1q, *w1k, *w1v, *w1f, *w2q, *w2k, *w2v, *w2f, *wfe;
    u16 *hA, *hB, *qb, *kb, *vb;
};

// C[M,Nper] = A[M,K] @ W[Nper,K]^T + bias; EPI 0: bf16 store, 1: bf16(res+gelu), 2: fp32
template<int EPI>
__device__ void gemm_stage(const u16* __restrict__ A,
                           const u16* W0, const u16* W1, const u16* W2,
                           const float* bi0, const float* bi1, const float* bi2,
                           u16* o0, u16* o1, u16* o2,
                           float* of, const u16* res,
                           int Nper, int K, int tilesN, int nW,
                           u16* As, u16* Ws)
{
    const int tid  = threadIdx.x;
    const int lane = tid & 63;
    const int wave = tid >> 6;
    const int wm = wave & 1, wn = wave >> 1;
    const int quad = lane >> 4, l16 = lane & 15;
    const int srow = tid >> 3;
    const int scol = (tid & 7) * 8;

    const int tcols  = tilesN * nW;
    const int tTotal = tcols * (BATCH / BM);

    for (int t = blockIdx.x; t < tTotal; t += gridDim.x) {
        const int tc = t % tcols;
        const int bm = (t / tcols) * BM;
        const int which = tc / tilesN;
        const int bn = (tc % tilesN) * BN;
        const u16* W    = (which == 0) ? W0  : (which == 1) ? W1  : W2;
        const float* bi = (which == 0) ? bi0 : (which == 1) ? bi1 : bi2;
        u16* ob         = (which == 0) ? o0  : (which == 1) ? o1  : o2;

        fx4 acc[2][2] = {};

        for (int kt = 0; kt < K; kt += BK) {
#pragma unroll
            for (int c = 0; c < 2; c++) {
                const int r = srow + 32 * c;
                *(short8*)&As[r * LDK + scol] =
                    *(const short8*)&A[(size_t)(bm + r) * K + kt + scol];
                *(short8*)&Ws[r * LDK + scol] =
                    *(const short8*)&W[(size_t)(bn + r) * K + kt + scol];
            }
            __syncthreads();
#pragma unroll
            for (int k0 = 0; k0 < BK; k0 += 32) {
                const short8 a0 = *(const short8*)&As[(wm * 32 +      l16) * LDK + k0 + quad * 8];
                const short8 a1 = *(const short8*)&As[(wm * 32 + 16 + l16) * LDK + k0 + quad * 8];
                const short8 b0 = *(const short8*)&Ws[(wn * 32 +      l16) * LDK + k0 + quad * 8];
                const short8 b1 = *(const short8*)&Ws[(wn * 32 + 16 + l16) * LDK + k0 + quad * 8];
                acc[0][0] = __builtin_amdgcn_mfma_f32_16x16x32_bf16(a0, b0, acc[0][0], 0, 0, 0);
                acc[0][1] = __builtin_amdgcn_mfma_f32_16x16x32_bf16(a0, b1, acc[0][1], 0, 0, 0);
                acc[1][0] = __builtin_amdgcn_mfma_f32_16x16x32_bf16(a1, b0, acc[1][0], 0, 0, 0);
                acc[1][1] = __builtin_amdgcn_mfma_f32_16x16x32_bf16(a1, b1, acc[1][1], 0, 0, 0);
            }
            __syncthreads();
        }

#pragma unroll
        for (int i = 0; i < 2; i++) {
#pragma unroll
            for (int j = 0; j < 2; j++) {
                const int n_ = bn + wn * 32 + j * 16 + l16;
                const float bv = bi[n_];
#pragma unroll
                for (int r = 0; r < 4; r++) {
                    const int m_ = bm + wm * 32 + i * 16 + quad * 4 + r;
                    const float vacc = acc[i][j][r] + bv;
                    const size_t idx = (size_t)m_ * Nper + n_;
                    if (EPI == 0) {
                        ob[idx] = f2b(vacc);
                    } else if (EPI == 1) {
                        const float g = 0.5f * vacc * (1.0f + erff(vacc * 0.70710678118654752f));
                        ob[idx] = f2b(b2f(res[idx]) + g);
                    } else {
                        of[idx] = vacc;
                    }
                }
            }
        }
    }
}

// hout = h + softmax_j(q_i*k_j) @ v ; two batches per block, 4 acc chains/thread
__device__ void attn_stage(const u16* __restrict__ h, const u16* __restrict__ q,
                           const u16* __restrict__ k, const u16* __restrict__ v,
                           u16* __restrict__ hout, float* sk, float* red)
{
    const int tid = threadIdx.x;
    const int lane = tid & 63, wave = tid >> 6;

    for (int pr = blockIdx.x; pr < BATCH / 2; pr += gridDim.x) {
        const int bA = pr * 2, bB = bA + 1;
        const size_t baA = (size_t)bA * HDIM, baB = (size_t)bB * HDIM;
        float* kA = sk;         float* vA = sk + 512;
        float* kB = sk + 1024;  float* vB = sk + 1536;

        float lAmax = -1e30f, lAmin = 1e30f, lBmax = -1e30f, lBmin = 1e30f;
        for (int t = tid; t < HDIM; t += NTHR) {
            const float ka = b2f(k[baA + t]); kA[t] = ka; vA[t] = b2f(v[baA + t]);
            const float kb_ = b2f(k[baB + t]); kB[t] = kb_; vB[t] = b2f(v[baB + t]);
            lAmax = fmaxf(lAmax, ka); lAmin = fminf(lAmin, ka);
            lBmax = fmaxf(lBmax, kb_); lBmin = fminf(lBmin, kb_);
        }
#pragma unroll
        for (int off = 32; off; off >>= 1) {
            lAmax = fmaxf(lAmax, __shfl_xor(lAmax, off));
            lAmin = fminf(lAmin, __shfl_xor(lAmin, off));
            lBmax = fmaxf(lBmax, __shfl_xor(lBmax, off));
            lBmin = fminf(lBmin, __shfl_xor(lBmin, off));
        }
        if (lane == 0) {
            red[wave] = lAmax; red[4 + wave] = lAmin;
            red[8 + wave] = lBmax; red[12 + wave] = lBmin;
        }
        __syncthreads();
        const float kAmax = fmaxf(fmaxf(red[0], red[1]), fmaxf(red[2], red[3]));
        const float kAmin = fminf(fminf(red[4], red[5]), fminf(red[6], red[7]));
        const float kBmax = fmaxf(fmaxf(red[8], red[9]), fmaxf(red[10], red[11]));
        const float kBmin = fminf(fminf(red[12], red[13]), fminf(red[14], red[15]));

        const int i0 = tid, i1 = tid + NTHR;
        float s[4], mn[4];
        s[0] = b2f(q[baA + i0]); s[1] = b2f(q[baA + i1]);
        s[2] = b2f(q[baB + i0]); s[3] = b2f(q[baB + i1]);
        mn[0] = -((s[0] > 0.f) ? s[0] * kAmax : s[0] * kAmin) * LOG2E;
        mn[1] = -((s[1] > 0.f) ? s[1] * kAmax : s[1] * kAmin) * LOG2E;
        mn[2] = -((s[2] > 0.f) ? s[2] * kBmax : s[2] * kBmin) * LOG2E;
        mn[3] = -((s[3] > 0.f) ? s[3] * kBmax : s[3] * kBmin) * LOG2E;
#pragma unroll
        for (int c = 0; c < 4; c++) s[c] *= LOG2E;

        float2 D[4], Nn[4];
#pragma unroll
        for (int c = 0; c < 4; c++) { D[c] = make_float2(0.f, 0.f); Nn[c] = make_float2(0.f, 0.f); }
        const float2 s2_[4]  = {make_float2(s[0], s[0]), make_float2(s[1], s[1]),
                                make_float2(s[2], s[2]), make_float2(s[3], s[3])};
        const float2 mn2_[4] = {make_float2(mn[0], mn[0]), make_float2(mn[1], mn[1]),
                                make_float2(mn[2], mn[2]), make_float2(mn[3], mn[3])};

        const float4* k4A = (const float4*)kA; const float4* v4A = (const float4*)vA;
        const float4* k4B = (const float4*)kB; const float4* v4B = (const float4*)vB;

#define CHAIN(c, kk, vv)                                                     \
        {                                                                    \
            float2 a0 = pk_fma(s2_[c], make_float2(kk.x, kk.y), mn2_[c]);    \
            float2 e0; e0.x = EXP2(a0.x); e0.y = EXP2(a0.y);                 \
            D[c]  = pk_add(D[c], e0);                                        \
            Nn[c] = pk_fma(e0, make_float2(vv.x, vv.y), Nn[c]);              \
            float2 a1 = pk_fma(s2_[c], make_float2(kk.z, kk.w), mn2_[c]);    \
            float2 e1; e1.x = EXP2(a1.x); e1.y = EXP2(a1.y);                 \
            D[c]  = pk_add(D[c], e1);                                        \
            Nn[c] = pk_fma(e1, make_float2(vv.z, vv.w), Nn[c]);              \
        }

#pragma unroll 2
        for (int j = 0; j < HDIM / 4; j++) {
            const float4 ka = k4A[j]; const float4 va = v4A[j];
            const float4 kb4 = k4B[j]; const float4 vb4 = v4B[j];
            CHAIN(0, ka, va)
            CHAIN(1, ka, va)
            CHAIN(2, kb4, vb4)
            CHAIN(3, kb4, vb4)
        }
#undef CHAIN

        hout[baA + i0] = f2b(b2f(h[baA + i0]) + (Nn[0].x + Nn[0].y) / (D[0].x + D[0].y));
        hout[baA + i1] = f2b(b2f(h[baA + i1]) + (Nn[1].x + Nn[1].y) / (D[1].x + D[1].y));
        hout[baB + i0] = f2b(b2f(h[baB + i0]) + (Nn[2].x + Nn[2].y) / (D[2].x + D[2].y));
        hout[baB + i1] = f2b(b2f(h[baB + i1]) + (Nn[3].x + Nn[3].y) / (D[3].x + D[3].y));
        __syncthreads();
    }
}

__device__ void head_stage(const float* __restrict__ fea, const float* __restrict__ rw,
                           const float* __restrict__ rb, float* __restrict__ out, float* red)
{
    const int tid = threadIdx.x;
    const int lane = tid & 63, wave = tid >> 6;
    for (int r0 = blockIdx.x * 2; r0 < BATCH; r0 += gridDim.x * 2) {
        const int row = r0 + (wave >> 1);
        const int p = (wave & 1) * 64 + lane;
        float vsum = fea[row * PDIM + p] * rw[p];
#pragma unroll
        for (int off = 32; off; off >>= 1) vsum += __shfl_xor(vsum, off);
        if (lane == 0) red[wave] = vsum;
        __syncthreads();
        if (tid == 0)   out[r0]     = red[0] + red[1] + rb[0];
        if (tid == 128) out[r0 + 1] = red[2] + red[3] + rb[0];
        __syncthreads();
    }
}

__global__ __launch_bounds__(NTHR, 2) void mega(Args a)
{
    cg::grid_group grid = cg::this_grid();
    __shared__ __align__(16) u16 smem[SMEM_U16];
    __shared__ float red[16];
    u16* As = smem;
    u16* Ws = smem + BM * LDK;
    float* sk = (float*)smem;

    // ---- stage 0: fp32 -> bf16 conversion ----
    {
        const float* srcs[11] = {a.x, a.lin0_w, a.b1_qw, a.b1_kw, a.b1_vw, a.b1_f1w,
                                 a.b2_qw, a.b2_kw, a.b2_vw, a.b2_f1w, a.fea_w};
        u16* dsts[11] = {a.xb, a.wl0, a.w1q, a.w1k, a.w1v, a.w1f,
                         a.w2q, a.w2k, a.w2v, a.w2f, a.wfe};
        const int n4s[11] = {65536, 32768, 65536, 65536, 65536, 65536,
                             65536, 65536, 65536, 65536, 16384};
        const int gt = blockIdx.x * NTHR + threadIdx.x;
        for (int t = 0; t < 11; t++) {
            const float4* s4 = (const float4*)srcs[t];
            ushort4* d4 = (ushort4*)dsts[t];
            for (int i = gt; i < n4s[t]; i += GRID * NTHR) {
                const float4 f = s4[i];
                ushort4 o;
                o.x = f2b(f.x); o.y = f2b(f.y); o.z = f2b(f.z); o.w = f2b(f.w);
                d4[i] = o;
            }
        }
    }
    grid.sync();

    // lin0
    gemm_stage<0>(a.xb, a.wl0, a.wl0, a.wl0, a.lin0_b, a.lin0_b, a.lin0_b,
                  a.hA, a.hA, a.hA, nullptr, nullptr, HDIM, FIN, HDIM / BN, 1, As, Ws);
    grid.sync();
    // block 1
    gemm_stage<0>(a.hA, a.w1q, a.w1k, a.w1v, a.b1_qb, a.b1_kb, a.b1_vb,
                  a.qb, a.kb, a.vb, nullptr, nullptr, HDIM, HDIM, HDIM / BN, 3, As, Ws);
    grid.sync();
    attn_stage(a.hA, a.qb, a.kb, a.vb, a.hB, sk, red);
    grid.sync();
    gemm_stage<1>(a.hB, a.w1f, a.w1f, a.w1f, a.b1_f1b, a.b1_f1b, a.b1_f1b,
                  a.hA, a.hA, a.hA, nullptr, a.hB, HDIM, HDIM, HDIM / BN, 1, As, Ws);
    grid.sync();
    // block 2
    gemm_stage<0>(a.hA, a.w2q, a.w2k, a.w2v, a.b2_qb, a.b2_kb, a.b2_vb,
                  a.qb, a.kb, a.vb, nullptr, nullptr, HDIM, HDIM, HDIM / BN, 3, As, Ws);
    grid.sync();
    attn_stage(a.hA, a.qb, a.kb, a.vb, a.hB, sk, red);
    grid.sync();
    gemm_stage<1>(a.hB, a.w2f, a.w2f, a.w2f, a.b2_f1b, a.b2_f1b, a.b2_f1b,
                  a.hA, a.hA, a.hA, nullptr, a.hB, HDIM, HDIM, HDIM / BN, 1, As, Ws);
    grid.sync();
    // fea (fp32 out into d_out)
    gemm_stage<2>(a.hA, a.wfe, a.wfe, a.wfe, a.fea_b, a.fea_b, a.fea_b,
                  nullptr, nullptr, nullptr, a.fea, nullptr, PDIM, HDIM, PDIM / BN, 1, As, Ws);
    grid.sync();
    head_stage(a.fea, a.reg_w, a.reg_b, a.out, red);
}

extern "C" void kernel_launch(void* const* d_in, const int* in_sizes, int n_in,
                              void* d_out, int out_size, void* d_ws, size_t ws_size,
                              hipStream_t stream) {
    Args a;
    a.x      = (const float*)d_in[0];
    a.lin0_w = (const float*)d_in[1];  a.lin0_b = (const float*)d_in[2];
    a.b1_qw  = (const float*)d_in[3];  a.b1_qb  = (const float*)d_in[4];
    a.b1_kw  = (const float*)d_in[5];  a.b1_kb  = (const float*)d_in[6];
    a.b1_vw  = (const float*)d_in[7];  a.b1_vb  = (const float*)d_in[8];
    a.b1_f1w = (const float*)d_in[9];  a.b1_f1b = (const float*)d_in[10];
    a.b2_qw  = (const float*)d_in[11]; a.b2_qb  = (const float*)d_in[12];
    a.b2_kw  = (const float*)d_in[13]; a.b2_kb  = (const float*)d_in[14];
    a.b2_vw  = (const float*)d_in[15]; a.b2_vb  = (const float*)d_in[16];
    a.b2_f1w = (const float*)d_in[17]; a.b2_f1b = (const float*)d_in[18];
    a.fea_w  = (const float*)d_in[19]; a.fea_b  = (const float*)d_in[20];
    a.reg_w  = (const float*)d_in[21]; a.reg_b  = (const float*)d_in[22];

    a.out = (float*)d_out;
    a.fea = a.out + BATCH;

    u16* wsb = (u16*)d_ws;
    const size_t SZ_X  = (size_t)BATCH * FIN;
    const size_t SZ_L0 = (size_t)HDIM * FIN;
    const size_t SZ_HH = (size_t)HDIM * HDIM;
    const size_t SZ_FE = (size_t)PDIM * HDIM;
    const size_t SZ_AC = (size_t)BATCH * HDIM;

    a.xb  = wsb;
    a.wl0 = a.xb + SZ_X;
    a.w1q = a.wl0 + SZ_L0;
    a.w1k = a.w1q + SZ_HH;
    a.w1v = a.w1k + SZ_HH;
    a.w1f = a.w1v + SZ_HH;
    a.w2q = a.w1f + SZ_HH;
    a.w2k = a.w2q + SZ_HH;
    a.w2v = a.w2k + SZ_HH;
    a.w2f = a.w2v + SZ_HH;
    a.wfe = a.w2f + SZ_HH;
    a.hA  = a.wfe + SZ_FE;
    a.hB  = a.hA + SZ_AC;
    a.qb  = a.hB + SZ_AC;
    a.kb  = a.qb + SZ_AC;
    a.vb  = a.kb + SZ_AC;

    void* kp[] = {(void*)&a};
    hipLaunchCooperativeKernel((const void*)mega, dim3(GRID), dim3(NTHR), kp, 0, stream);
}

// Round 4
// 213.582 us; speedup vs baseline: 3.4121x; 3.4121x over previous
//
#include <hip/hip_runtime.h>
#include <math.h>

#define BATCH 1024
#define FIN   256
#define HDIM  512
#define PDIM  128

typedef unsigned short u16;
typedef __attribute__((ext_vector_type(8))) short short8;
typedef __attribute__((ext_vector_type(4))) float fx4;

#define LOG2E 1.4426950408889634f

__device__ __forceinline__ float b2f(u16 b) {
    return __uint_as_float(((unsigned)b) << 16);
}
__device__ __forceinline__ u16 f2b(float f) {
    unsigned u = __float_as_uint(f);
    u += 0x7fffu + ((u >> 16) & 1u);   // RNE
    return (u16)(u >> 16);
}

#if defined(__has_builtin)
#if __has_builtin(__builtin_amdgcn_exp2f)
#define EXP2(x) __builtin_amdgcn_exp2f(x)
#endif
#endif
#ifndef EXP2
#define EXP2(x) __expf(0.69314718055994531f * (x))
#endif

__device__ __forceinline__ float2 pk_fma(float2 a, float2 b, float2 c) {
    float2 d;
    asm("v_pk_fma_f32 %0, %1, %2, %3" : "=v"(d) : "v"(a), "v"(b), "v"(c));
    return d;
}
__device__ __forceinline__ float2 pk_add(float2 a, float2 b) {
    float2 d;
    asm("v_pk_add_f32 %0, %1, %2" : "=v"(d) : "v"(a), "v"(b));
    return d;
}

// ---- GEMM tile config ----
#define BM 64
#define BN 64
#define BK 64
#define LDK 72   // +8 pad

// ================= lin0 (inline fp32->bf16 staging) + weight cvt ============
#define NCVT 9
struct CvtArgs {
    const float* src[NCVT];
    u16* dst[NCVT];
    int n4[NCVT];   // float4 count
};

__global__ __launch_bounds__(256) void lin0_cvt_kernel(
    const float* __restrict__ x, const float* __restrict__ wf,
    const float* __restrict__ bi, u16* __restrict__ oh, CvtArgs ca)
{
    const int tid = threadIdx.x;
    if (blockIdx.x >= 128) {
        // ---- weight conversion part ----
        const int gt = (blockIdx.x - 128) * 256 + tid;
        const int stride = 384 * 256;
        for (int t = 0; t < NCVT; t++) {
            const float4* s4 = (const float4*)ca.src[t];
            ushort4* d4 = (ushort4*)ca.dst[t];
            for (int i = gt; i < ca.n4[t]; i += stride) {
                const float4 f = s4[i];
                ushort4 o;
                o.x = f2b(f.x); o.y = f2b(f.y); o.z = f2b(f.z); o.w = f2b(f.w);
                d4[i] = o;
            }
        }
        return;
    }
    // ---- lin0 GEMM: [1024,512] = x[1024,256] @ wf[512,256]^T + bi ----
    __shared__ __align__(16) u16 As[BM * LDK];
    __shared__ __align__(16) u16 Ws[BM * LDK];
    const int lane = tid & 63, wave = tid >> 6;
    const int wm = wave & 1, wn = wave >> 1;
    const int quad = lane >> 4, l16 = lane & 15;
    const int bn = (blockIdx.x & 7) * BN;
    const int bm = (blockIdx.x >> 3) * BM;
    const int srow = tid >> 3;
    const int scol = (tid & 7) * 8;

    fx4 acc[2][2] = {};
    for (int kt = 0; kt < FIN; kt += BK) {
#pragma unroll
        for (int c = 0; c < 2; c++) {
            const int r = srow + 32 * c;
            {
                const float4 f0 = *(const float4*)&x[(size_t)(bm + r) * FIN + kt + scol];
                const float4 f1 = *(const float4*)&x[(size_t)(bm + r) * FIN + kt + scol + 4];
                short8 s;
                s[0] = (short)f2b(f0.x); s[1] = (short)f2b(f0.y);
                s[2] = (short)f2b(f0.z); s[3] = (short)f2b(f0.w);
                s[4] = (short)f2b(f1.x); s[5] = (short)f2b(f1.y);
                s[6] = (short)f2b(f1.z); s[7] = (short)f2b(f1.w);
                *(short8*)&As[r * LDK + scol] = s;
            }
            {
                const float4 f0 = *(const float4*)&wf[(size_t)(bn + r) * FIN + kt + scol];
                const float4 f1 = *(const float4*)&wf[(size_t)(bn + r) * FIN + kt + scol + 4];
                short8 s;
                s[0] = (short)f2b(f0.x); s[1] = (short)f2b(f0.y);
                s[2] = (short)f2b(f0.z); s[3] = (short)f2b(f0.w);
                s[4] = (short)f2b(f1.x); s[5] = (short)f2b(f1.y);
                s[6] = (short)f2b(f1.z); s[7] = (short)f2b(f1.w);
                *(short8*)&Ws[r * LDK + scol] = s;
            }
        }
        __syncthreads();
#pragma unroll
        for (int k0 = 0; k0 < BK; k0 += 32) {
            const short8 a0 = *(const short8*)&As[(wm * 32 +      l16) * LDK + k0 + quad * 8];
            const short8 a1 = *(const short8*)&As[(wm * 32 + 16 + l16) * LDK + k0 + quad * 8];
            const short8 b0 = *(const short8*)&Ws[(wn * 32 +      l16) * LDK + k0 + quad * 8];
            const short8 b1 = *(const short8*)&Ws[(wn * 32 + 16 + l16) * LDK + k0 + quad * 8];
            acc[0][0] = __builtin_amdgcn_mfma_f32_16x16x32_bf16(a0, b0, acc[0][0], 0, 0, 0);
            acc[0][1] = __builtin_amdgcn_mfma_f32_16x16x32_bf16(a0, b1, acc[0][1], 0, 0, 0);
            acc[1][0] = __builtin_amdgcn_mfma_f32_16x16x32_bf16(a1, b0, acc[1][0], 0, 0, 0);
            acc[1][1] = __builtin_amdgcn_mfma_f32_16x16x32_bf16(a1, b1, acc[1][1], 0, 0, 0);
        }
        __syncthreads();
    }
#pragma unroll
    for (int i = 0; i < 2; i++)
#pragma unroll
        for (int j = 0; j < 2; j++) {
            const int n_ = bn + wn * 32 + j * 16 + l16;
            const float bv = bi[n_];
#pragma unroll
            for (int r = 0; r < 4; r++) {
                const int m_ = bm + wm * 32 + i * 16 + quad * 4 + r;
                oh[(size_t)m_ * HDIM + n_] = f2b(acc[i][j][r] + bv);
            }
        }
}

// ================= main bf16 GEMM (double-buffered) =========================
// EPI 0: store bf16(acc+bias); EPI 1: store bf16(res + gelu(acc+bias))
template<int EPI>
__global__ __launch_bounds__(256) void gemm_k(
    const u16* __restrict__ A,
    const u16* __restrict__ W0, const u16* __restrict__ W1, const u16* __restrict__ W2,
    const float* __restrict__ bi0, const float* __restrict__ bi1, const float* __restrict__ bi2,
    u16* __restrict__ o0, u16* __restrict__ o1, u16* __restrict__ o2,
    const u16* __restrict__ res, int Nper, int K, int tilesN)
{
    __shared__ __align__(16) u16 As[2][BM * LDK];
    __shared__ __align__(16) u16 Ws[2][BM * LDK];

    const int tid = threadIdx.x, lane = tid & 63, wave = tid >> 6;
    const int wm = wave & 1, wn = wave >> 1;
    const int quad = lane >> 4, l16 = lane & 15;

    const int which = blockIdx.x / tilesN;
    const int bn = (blockIdx.x % tilesN) * BN;
    const int bm = blockIdx.y * BM;
    const u16* W    = (which == 0) ? W0  : (which == 1) ? W1  : W2;
    const float* bi = (which == 0) ? bi0 : (which == 1) ? bi1 : bi2;
    u16* ob         = (which == 0) ? o0  : (which == 1) ? o1  : o2;

    const int srow = tid >> 3;
    const int scol = (tid & 7) * 8;
    const u16* Ab = A + (size_t)(bm + srow) * K + scol;
    const u16* Wb = W + (size_t)(bn + srow) * K + scol;

    // stage k-tile 0 into buffer 0
    {
        const short8 a0 = *(const short8*)Ab;
        const short8 a1 = *(const short8*)(Ab + (size_t)32 * K);
        const short8 w0 = *(const short8*)Wb;
        const short8 w1 = *(const short8*)(Wb + (size_t)32 * K);
        *(short8*)&As[0][srow * LDK + scol] = a0;
        *(short8*)&As[0][(srow + 32) * LDK + scol] = a1;
        *(short8*)&Ws[0][srow * LDK + scol] = w0;
        *(short8*)&Ws[0][(srow + 32) * LDK + scol] = w1;
    }

    fx4 acc[2][2] = {};
    const int nIter = K / BK;
    for (int it = 0; it < nIter; ++it) {
        const int cur = it & 1, nxt = cur ^ 1;
        short8 na0, na1, nw0, nw1;
        const bool has = (it + 1 < nIter);
        if (has) {
            const int kt = (it + 1) * BK;
            na0 = *(const short8*)(Ab + kt);
            na1 = *(const short8*)(Ab + (size_t)32 * K + kt);
            nw0 = *(const short8*)(Wb + kt);
            nw1 = *(const short8*)(Wb + (size_t)32 * K + kt);
        }
        __syncthreads();
#pragma unroll
        for (int k0 = 0; k0 < BK; k0 += 32) {
            const short8 a0 = *(const short8*)&As[cur][(wm * 32 +      l16) * LDK + k0 + quad * 8];
            const short8 a1 = *(const short8*)&As[cur][(wm * 32 + 16 + l16) * LDK + k0 + quad * 8];
            const short8 b0 = *(const short8*)&Ws[cur][(wn * 32 +      l16) * LDK + k0 + quad * 8];
            const short8 b1 = *(const short8*)&Ws[cur][(wn * 32 + 16 + l16) * LDK + k0 + quad * 8];
            acc[0][0] = __builtin_amdgcn_mfma_f32_16x16x32_bf16(a0, b0, acc[0][0], 0, 0, 0);
            acc[0][1] = __builtin_amdgcn_mfma_f32_16x16x32_bf16(a0, b1, acc[0][1], 0, 0, 0);
            acc[1][0] = __builtin_amdgcn_mfma_f32_16x16x32_bf16(a1, b0, acc[1][0], 0, 0, 0);
            acc[1][1] = __builtin_amdgcn_mfma_f32_16x16x32_bf16(a1, b1, acc[1][1], 0, 0, 0);
        }
        if (has) {
            *(short8*)&As[nxt][srow * LDK + scol] = na0;
            *(short8*)&As[nxt][(srow + 32) * LDK + scol] = na1;
            *(short8*)&Ws[nxt][srow * LDK + scol] = nw0;
            *(short8*)&Ws[nxt][(srow + 32) * LDK + scol] = nw1;
        }
    }

#pragma unroll
    for (int i = 0; i < 2; i++)
#pragma unroll
        for (int j = 0; j < 2; j++) {
            const int n_ = bn + wn * 32 + j * 16 + l16;
            const float bv = bi[n_];
#pragma unroll
            for (int r = 0; r < 4; r++) {
                const int m_ = bm + wm * 32 + i * 16 + quad * 4 + r;
                const float vacc = acc[i][j][r] + bv;
                const size_t idx = (size_t)m_ * Nper + n_;
                if (EPI == 0) {
                    ob[idx] = f2b(vacc);
                } else {
                    const float g = 0.5f * vacc * (1.0f + erff(vacc * 0.70710678118654752f));
                    ob[idx] = f2b(b2f(res[idx]) + g);
                }
            }
        }
}

// ================= attention (pk math, exp2 domain) =========================
__global__ __launch_bounds__(256) void attn_kernel(
    const u16* __restrict__ h, const u16* __restrict__ q,
    const u16* __restrict__ k, const u16* __restrict__ v,
    u16* __restrict__ hout)
{
    __shared__ __align__(16) float ks[HDIM];
    __shared__ __align__(16) float vs[HDIM];
    __shared__ float red[8];

    const int b = blockIdx.x;
    const int tid = threadIdx.x;
    const int lane = tid & 63, wave = tid >> 6;
    const int i0 = tid, i1 = tid + 256;
    const size_t base = (size_t)b * HDIM;

    const float k0 = b2f(k[base + i0]);
    const float k1 = b2f(k[base + i1]);
    ks[i0] = k0; ks[i1] = k1;
    vs[i0] = b2f(v[base + i0]);
    vs[i1] = b2f(v[base + i1]);

    float lmax = fmaxf(k0, k1), lmin = fminf(k0, k1);
#pragma unroll
    for (int off = 32; off; off >>= 1) {
        lmax = fmaxf(lmax, __shfl_xor(lmax, off));
        lmin = fminf(lmin, __shfl_xor(lmin, off));
    }
    if (lane == 0) { red[wave] = lmax; red[4 + wave] = lmin; }
    __syncthreads();
    const float kmax = fmaxf(fmaxf(red[0], red[1]), fmaxf(red[2], red[3]));
    const float kmin = fminf(fminf(red[4], red[5]), fminf(red[6], red[7]));

    float s0 = b2f(q[base + i0]);
    float s1 = b2f(q[base + i1]);
    const float mn0 = -((s0 > 0.f) ? s0 * kmax : s0 * kmin) * LOG2E;
    const float mn1 = -((s1 > 0.f) ? s1 * kmax : s1 * kmin) * LOG2E;
    s0 *= LOG2E; s1 *= LOG2E;

    const float2 s0_2  = make_float2(s0, s0),  s1_2  = make_float2(s1, s1);
    const float2 mn0_2 = make_float2(mn0, mn0), mn1_2 = make_float2(mn1, mn1);
    float2 D0 = make_float2(0.f, 0.f), N0 = D0, D1 = D0, N1 = D0;

    const float4* k4 = (const float4*)ks;
    const float4* v4 = (const float4*)vs;
#pragma unroll 4
    for (int j = 0; j < HDIM / 4; j++) {
        const float4 kk = k4[j];
        const float4 vv = v4[j];
        {
            float2 a0 = pk_fma(s0_2, make_float2(kk.x, kk.y), mn0_2);
            float2 e0; e0.x = EXP2(a0.x); e0.y = EXP2(a0.y);
            D0 = pk_add(D0, e0);
            N0 = pk_fma(e0, make_float2(vv.x, vv.y), N0);
            float2 a1 = pk_fma(s0_2, make_float2(kk.z, kk.w), mn0_2);
            float2 e1; e1.x = EXP2(a1.x); e1.y = EXP2(a1.y);
            D0 = pk_add(D0, e1);
            N0 = pk_fma(e1, make_float2(vv.z, vv.w), N0);
        }
        {
            float2 a0 = pk_fma(s1_2, make_float2(kk.x, kk.y), mn1_2);
            float2 e0; e0.x = EXP2(a0.x); e0.y = EXP2(a0.y);
            D1 = pk_add(D1, e0);
            N1 = pk_fma(e0, make_float2(vv.x, vv.y), N1);
            float2 a1 = pk_fma(s1_2, make_float2(kk.z, kk.w), mn1_2);
            float2 e1; e1.x = EXP2(a1.x); e1.y = EXP2(a1.y);
            D1 = pk_add(D1, e1);
            N1 = pk_fma(e1, make_float2(vv.z, vv.w), N1);
        }
    }
    hout[base + i0] = f2b(b2f(h[base + i0]) + (N0.x + N0.y) / (D0.x + D0.y));
    hout[base + i1] = f2b(b2f(h[base + i1]) + (N1.x + N1.y) / (D1.x + D1.y));
}

// ================= fea GEMM (BN = full 128) + fused regression head =========
#define FM 64
#define FN 128
__global__ __launch_bounds__(256) void fea_head_kernel(
    const u16* __restrict__ A, const u16* __restrict__ Wf,
    const float* __restrict__ fb, const float* __restrict__ rw,
    const float* __restrict__ rb, float* __restrict__ fea, float* __restrict__ out)
{
    __shared__ __align__(16) u16 As[2][FM * LDK];
    __shared__ __align__(16) u16 Ws[2][FN * LDK];
    __shared__ float red[2][FM];

    const int tid = threadIdx.x, lane = tid & 63, wave = tid >> 6;
    const int wm = wave & 1, wn = wave >> 1;
    const int quad = lane >> 4, l16 = lane & 15;
    const int bm = blockIdx.x * FM;
    const int srow = tid >> 3;
    const int scol = (tid & 7) * 8;
    const int K = HDIM;

    const u16* Ab = A + (size_t)(bm + srow) * K + scol;
    const u16* Wb = Wf + (size_t)srow * K + scol;

    {
        *(short8*)&As[0][srow * LDK + scol]        = *(const short8*)Ab;
        *(short8*)&As[0][(srow + 32) * LDK + scol] = *(const short8*)(Ab + (size_t)32 * K);
#pragma unroll
        for (int c = 0; c < 4; c++)
            *(short8*)&Ws[0][(srow + 32 * c) * LDK + scol] =
                *(const short8*)(Wb + (size_t)(32 * c) * K);
    }

    fx4 acc[2][4] = {};
    const int nIter = K / BK;
    for (int it = 0; it < nIter; ++it) {
        const int cur = it & 1, nxt = cur ^ 1;
        short8 na0, na1, nw[4];
        const bool has = (it + 1 < nIter);
        if (has) {
            const int kt = (it + 1) * BK;
            na0 = *(const short8*)(Ab + kt);
            na1 = *(const short8*)(Ab + (size_t)32 * K + kt);
#pragma unroll
            for (int c = 0; c < 4; c++)
                nw[c] = *(const short8*)(Wb + (size_t)(32 * c) * K + kt);
        }
        __syncthreads();
#pragma unroll
        for (int k0 = 0; k0 < BK; k0 += 32) {
            const short8 a0 = *(const short8*)&As[cur][(wm * 32 +      l16) * LDK + k0 + quad * 8];
            const short8 a1 = *(const short8*)&As[cur][(wm * 32 + 16 + l16) * LDK + k0 + quad * 8];
#pragma unroll
            for (int j = 0; j < 4; j++) {
                const short8 bj = *(const short8*)&Ws[cur][(wn * 64 + j * 16 + l16) * LDK + k0 + quad * 8];
                acc[0][j] = __builtin_amdgcn_mfma_f32_16x16x32_bf16(a0, bj, acc[0][j], 0, 0, 0);
                acc[1][j] = __builtin_amdgcn_mfma_f32_16x16x32_bf16(a1, bj, acc[1][j], 0, 0, 0);
            }
        }
        if (has) {
            *(short8*)&As[nxt][srow * LDK + scol] = na0;
            *(short8*)&As[nxt][(srow + 32) * LDK + scol] = na1;
#pragma unroll
            for (int c = 0; c < 4; c++)
                *(short8*)&Ws[nxt][(srow + 32 * c) * LDK + scol] = nw[c];
        }
    }

    // epilogue: store fea fp32 + fused head partial
#pragma unroll
    for (int i = 0; i < 2; i++) {
#pragma unroll
        for (int r = 0; r < 4; r++) {
            const int m_ = bm + wm * 32 + i * 16 + quad * 4 + r;
            float hp = 0.f;
#pragma unroll
            for (int j = 0; j < 4; j++) {
                const int n_ = wn * 64 + j * 16 + l16;
                const float vacc = acc[i][j][r] + fb[n_];
                fea[(size_t)(m_ - bm + bm) * PDIM + n_] = vacc;
                hp = fmaf(vacc, rw[n_], hp);
            }
#pragma unroll
            for (int off = 1; off < 16; off <<= 1) hp += __shfl_xor(hp, off);
            if (l16 == 0) red[wn][wm * 32 + i * 16 + quad * 4 + r] = hp;
        }
    }
    __syncthreads();
    if (tid < FM) out[bm + tid] = red[0][tid] + red[1][tid] + rb[0];
}

extern "C" void kernel_launch(void* const* d_in, const int* in_sizes, int n_in,
                              void* d_out, int out_size, void* d_ws, size_t ws_size,
                              hipStream_t stream) {
    const float* x      = (const float*)d_in[0];
    const float* lin0_w = (const float*)d_in[1];
    const float* lin0_b = (const float*)d_in[2];
    const float* b1_qw  = (const float*)d_in[3];
    const float* b1_qb  = (const float*)d_in[4];
    const float* b1_kw  = (const float*)d_in[5];
    const float* b1_kb  = (const float*)d_in[6];
    const float* b1_vw  = (const float*)d_in[7];
    const float* b1_vb  = (const float*)d_in[8];
    const float* b1_f1w = (const float*)d_in[9];
    const float* b1_f1b = (const float*)d_in[10];
    const float* b2_qw  = (const float*)d_in[11];
    const float* b2_qb  = (const float*)d_in[12];
    const float* b2_kw  = (const float*)d_in[13];
    const float* b2_kb  = (const float*)d_in[14];
    const float* b2_vw  = (const float*)d_in[15];
    const float* b2_vb  = (const float*)d_in[16];
    const float* b2_f1w = (const float*)d_in[17];
    const float* b2_f1b = (const float*)d_in[18];
    const float* fea_w  = (const float*)d_in[19];
    const float* fea_b  = (const float*)d_in[20];
    const float* reg_w  = (const float*)d_in[21];
    const float* reg_b  = (const float*)d_in[22];

    float* out = (float*)d_out;
    float* fea = out + BATCH;

    u16* wsb = (u16*)d_ws;
    const size_t SZ_HH = (size_t)HDIM * HDIM;   // 262144
    const size_t SZ_FE = (size_t)PDIM * HDIM;   // 65536
    const size_t SZ_AC = (size_t)BATCH * HDIM;  // 524288

    u16* w1q = wsb;
    u16* w1k = w1q + SZ_HH;
    u16* w1v = w1k + SZ_HH;
    u16* w1f = w1v + SZ_HH;
    u16* w2q = w1f + SZ_HH;
    u16* w2k = w2q + SZ_HH;
    u16* w2v = w2k + SZ_HH;
    u16* w2f = w2v + SZ_HH;
    u16* wfe = w2f + SZ_HH;
    u16* hA  = wfe + SZ_FE;
    u16* hB  = hA + SZ_AC;
    u16* qb  = hB + SZ_AC;
    u16* kb  = qb + SZ_AC;
    u16* vb  = kb + SZ_AC;

    CvtArgs ca;
    const float* srcs[NCVT] = {b1_qw, b1_kw, b1_vw, b1_f1w, b2_qw, b2_kw, b2_vw, b2_f1w, fea_w};
    u16* dsts[NCVT] = {w1q, w1k, w1v, w1f, w2q, w2k, w2v, w2f, wfe};
    const int n4s[NCVT] = {65536, 65536, 65536, 65536, 65536, 65536, 65536, 65536, 16384};
    for (int i = 0; i < NCVT; i++) { ca.src[i] = srcs[i]; ca.dst[i] = dsts[i]; ca.n4[i] = n4s[i]; }

    const dim3 blk(256);
    const dim3 g_qkv(3 * HDIM / BN, BATCH / BM);   // (24,16)
    const dim3 g_fc1(HDIM / BN, BATCH / BM);       // (8,16)

    // lin0 + weight conversion (one dispatch)
    lin0_cvt_kernel<<<512, blk, 0, stream>>>(x, lin0_w, lin0_b, hA, ca);

    // block 1
    gemm_k<0><<<g_qkv, blk, 0, stream>>>(hA, w1q, w1k, w1v, b1_qb, b1_kb, b1_vb,
                                         qb, kb, vb, nullptr, HDIM, HDIM, HDIM / BN);
    attn_kernel<<<BATCH, blk, 0, stream>>>(hA, qb, kb, vb, hB);
    gemm_k<1><<<g_fc1, blk, 0, stream>>>(hB, w1f, w1f, w1f, b1_f1b, b1_f1b, b1_f1b,
                                         hA, hA, hA, hB, HDIM, HDIM, HDIM / BN);
    // block 2
    gemm_k<0><<<g_qkv, blk, 0, stream>>>(hA, w2q, w2k, w2v, b2_qb, b2_kb, b2_vb,
                                         qb, kb, vb, nullptr, HDIM, HDIM, HDIM / BN);
    attn_kernel<<<BATCH, blk, 0, stream>>>(hA, qb, kb, vb, hB);
    gemm_k<1><<<g_fc1, blk, 0, stream>>>(hB, w2f, w2f, w2f, b2_f1b, b2_f1b, b2_f1b,
                                         hA, hA, hA, hB, HDIM, HDIM, HDIM / BN);

    // fea + head (one dispatch)
    fea_head_kernel<<<BATCH / FM, blk, 0, stream>>>(hA, wfe, fea_b, reg_w, reg_b, fea, out);
}